// Round 2
// 401.686 us; speedup vs baseline: 1.0176x; 1.0176x over previous
//
#include <hip/hip_runtime.h>
#include <math.h>

#define DIM   1024
#define NV    512
#define VD    256
#define NTOK  32768

// Output layout (floats): out | soft | perp | gumbel
#define SOFT_OFF  8388608u    // 32768*256
#define PERP_OFF  25165824u   // + 32768*512
#define GUM_OFF   25165825u   // + 1  (odd -> only 4B aligned!)

#define LO_SCALE      4096.0f
#define INV_LO_SCALE  (1.0f / 4096.0f)

typedef __attribute__((ext_vector_type(2)))  _Float16 half2v;
typedef __attribute__((ext_vector_type(4)))  _Float16 half4;
typedef __attribute__((ext_vector_type(8)))  _Float16 half8;
typedef __attribute__((ext_vector_type(16))) float    float16v;

// d_ws layout: Whi (1MB f16, k-blocked) | Wlo (1MB f16, k-blocked) | sums
#define WLO_ELEM_OFF  (NV * DIM)
#define SUMS_BYTE_OFF (2u * NV * DIM * 2u)

// direct-to-LDS 16B DMA (linear LDS dest = wave-uniform base + lane*16)
#define GLD_LDS16(gp, lp) \
    __builtin_amdgcn_global_load_lds((const __attribute__((address_space(1))) void*)(gp), \
                                     (__attribute__((address_space(3))) void*)(lp), 16, 0, 0)

// ---------------------------------------------------------------------------
// K0: split W (fp32) into f16 hi/lo planes, k-blocked by 8:
//     half index = ((k>>3)*NV + var)*8 + (k&7)
// Each 8-k chunk of all 512 vars is a contiguous 8KB slab -> linear DMA.
// ---------------------------------------------------------------------------
__global__ __launch_bounds__(256) void k_wsplit(const float* __restrict__ W,
                                                _Float16* __restrict__ whi,
                                                _Float16* __restrict__ wlo) {
    const int i   = (blockIdx.x * 256 + threadIdx.x) * 4;
    const int var = i >> 10;
    const int k   = i & 1023;
    float4 w = *(const float4*)(W + i);
    _Float16 h0 = (_Float16)w.x, h1 = (_Float16)w.y, h2 = (_Float16)w.z, h3 = (_Float16)w.w;
    _Float16 l0 = (_Float16)((w.x - (float)h0) * LO_SCALE);
    _Float16 l1 = (_Float16)((w.y - (float)h1) * LO_SCALE);
    _Float16 l2 = (_Float16)((w.z - (float)h2) * LO_SCALE);
    _Float16 l3 = (_Float16)((w.w - (float)h3) * LO_SCALE);
    const int dst = ((k >> 3) * NV + var) * 8 + (k & 7);   // k 4-aligned -> one chunk
    *(half4*)(whi + dst) = (half4){h0, h1, h2, h3};
    *(half4*)(wlo + dst) = (half4){l0, l1, l2, l3};
}

// ---------------------------------------------------------------------------
// K1: fused logits(32x512) -> softmax/argmax/one-hot/codebook/colsum.
// BK=16, double-buffered B (DMA) + A (ds_write), one barrier per K-step:
// DMA for step t+1 issued at top of step t, drained by step t's end barrier
// -> load latency hidden under ds_read + 12 MFMA.
// Split-precision f16 math identical to the previously passing kernel.
// ---------------------------------------------------------------------------
#define ASTR 40   // A row stride in halfs (80B: 16B-aligned, conflict-free frags)

__global__ __launch_bounds__(256, 2) void k_fused(
        const float* __restrict__ x,
        const _Float16* __restrict__ whi,
        const _Float16* __restrict__ wlo,
        const float* __restrict__ mask,
        const float* __restrict__ codebook,
        float* __restrict__ soft,
        float* __restrict__ gumbel,
        float* __restrict__ outp,
        float* __restrict__ sums) {
    // sBh [2 buf][2 chunk][512 var][8] (32KB) | sBl (32KB) |
    // sAh [2 buf][32][ASTR] (5KB) | sAl (5KB)  -> 75776B, 2 blocks/CU
    __shared__ __align__(16) char smem[75776];
    _Float16* sBh = (_Float16*)smem;
    _Float16* sBl = sBh + 16384;
    _Float16* sAh = sBl + 16384;
    _Float16* sAl = sAh + 2560;
    float*    ep  = (float*)smem;          // epilogue scratch (aliases B, post-loop)

    const int tid  = threadIdx.x;
    const int lane = tid & 63;
    const int wave = tid >> 6;
    const int lm   = lane & 31;
    const int hi   = lane >> 5;
    const int m0   = blockIdx.x * 32;

    float16v accM[4], accC[4];
#pragma unroll
    for (int p = 0; p < 4; ++p) { accM[p] = (float16v)(0.0f); accC[p] = (float16v)(0.0f); }

    // B DMA: wave w stages (plane = w>>1, chunk = w&1): 512 vars x 16B = 8 issues
    const _Float16* gB = ((wave >= 2) ? wlo : whi) + (size_t)((wave & 1) * 512 + lane) * 8;
    _Float16*       lB = ((wave >= 2) ? sBl : sBh) + (wave & 1) * 4096 + lane * 8;

    // A: thread t loads x[m0 + t>>3][step*16 + (t&7)*2 .. +1]
    const float* axp   = x + (size_t)(m0 + (tid >> 3)) * DIM + (tid & 7) * 2;
    const int    awoff = (tid >> 3) * ASTR + (tid & 7) * 2;

    // ---- prologue: stage step 0 into buf 0 ----
    float2 a2 = *(const float2*)axp;
#pragma unroll
    for (int j = 0; j < 8; ++j) GLD_LDS16(gB + j * 512, lB + j * 512);
    {
        _Float16 h0 = (_Float16)a2.x, h1 = (_Float16)a2.y;
        _Float16 l0 = (_Float16)((a2.x - (float)h0) * LO_SCALE);
        _Float16 l1 = (_Float16)((a2.y - (float)h1) * LO_SCALE);
        *(half2v*)&sAh[awoff] = (half2v){h0, h1};
        *(half2v*)&sAl[awoff] = (half2v){l0, l1};
    }
    a2 = *(const float2*)(axp + 16);
    __syncthreads();   // buf0 ready (drains DMA vmcnt + A lgkm)

    for (int t = 0; t < 64; ++t) {
        const int buf = t & 1;
        if (t < 63) {   // prefetch step t+1 into buf^1 (drained by THIS step's barrier)
            const _Float16* g = gB + (size_t)(t + 1) * 8192;
            _Float16*       l = lB + (buf ^ 1) * 8192;
#pragma unroll
            for (int j = 0; j < 8; ++j) GLD_LDS16(g + j * 512, l + j * 512);
        }

        const _Float16* pA = sAh + buf * 1280 + lm * ASTR + hi * 8;
        half8 ah = *(const half8*)pA;
        half8 al = *(const half8*)(pA + 2560);
        const _Float16* pB = sBh + buf * 8192 + hi * 4096 + (wave * 128 + lm) * 8;
#pragma unroll
        for (int p = 0; p < 4; ++p) {
            half8 bh = *(const half8*)(pB + p * 256);
            half8 bl = *(const half8*)(pB + 16384 + p * 256);
            accM[p] = __builtin_amdgcn_mfma_f32_32x32x16_f16(ah, bh, accM[p], 0, 0, 0);
            accC[p] = __builtin_amdgcn_mfma_f32_32x32x16_f16(ah, bl, accC[p], 0, 0, 0);
            accC[p] = __builtin_amdgcn_mfma_f32_32x32x16_f16(al, bh, accC[p], 0, 0, 0);
        }

        if (t < 63) {   // write A for step t+1 into buf^1
            _Float16 h0 = (_Float16)a2.x, h1 = (_Float16)a2.y;
            _Float16 l0 = (_Float16)((a2.x - (float)h0) * LO_SCALE);
            _Float16 l1 = (_Float16)((a2.y - (float)h1) * LO_SCALE);
            const int wo = (buf ^ 1) * 1280 + awoff;
            *(half2v*)&sAh[wo] = (half2v){h0, h1};
            *(half2v*)&sAl[wo] = (half2v){l0, l1};
            if (t < 62) a2 = *(const float2*)(axp + (size_t)(t + 2) * 16);
        }
        __syncthreads();
    }

    // ---------------- fused epilogue ----------------
    float* smaxA = ep;                     // [4][32]
    float* ssumA = ep + 128;               // [4][32]
    int*   sidxA = (int*)(ep + 256);       // [4][32]
    float* scol  = ep + 384;               // [512]
    int*   skidx = (int*)(ep + 896);       // [32]
    float* smask = ep + 928;               // [32]

    if (tid < 32) smask[tid] = mask[m0 + tid];
    __syncthreads();

    // token row per (r, hi): row = (r&3) + 8*(r>>2) + 4*hi  (32x32 MFMA C-layout)
    int rowv[16];
#pragma unroll
    for (int r = 0; r < 16; ++r) rowv[r] = (r & 3) + 8 * (r >> 2) + 4 * hi;

    float mk[16];
#pragma unroll
    for (int r = 0; r < 16; ++r) mk[r] = smask[rowv[r]];

    // logits (identical math to prior kernel) + mask + col0 zero
    float v[4][16];
#pragma unroll
    for (int p = 0; p < 4; ++p)
#pragma unroll
        for (int r = 0; r < 16; ++r) {
            float tv = (accM[p][r] + accC[p][r] * INV_LO_SCALE) * mk[r];
            if (wave == 0 && p == 0 && lm == 0) tv = 0.0f;   // var 0
            v[p][r] = tv;
        }

    // argmax (first index on ties): over p in-thread, then butterfly over lm
    float bv[16]; int bi[16];
#pragma unroll
    for (int r = 0; r < 16; ++r) { bv[r] = v[0][r]; bi[r] = wave * 128 + lm; }
#pragma unroll
    for (int p = 1; p < 4; ++p)
#pragma unroll
        for (int r = 0; r < 16; ++r)
            if (v[p][r] > bv[r]) { bv[r] = v[p][r]; bi[r] = wave * 128 + p * 32 + lm; }
#pragma unroll
    for (int off = 16; off >= 1; off >>= 1)
#pragma unroll
        for (int r = 0; r < 16; ++r) {
            float ov = __shfl_xor(bv[r], off, 64);
            int   oi = __shfl_xor(bi[r], off, 64);
            if (ov > bv[r] || (ov == bv[r] && oi < bi[r])) { bv[r] = ov; bi[r] = oi; }
        }
    if (lm == 0)
#pragma unroll
        for (int r = 0; r < 16; ++r) {
            smaxA[wave * 32 + rowv[r]] = bv[r];
            sidxA[wave * 32 + rowv[r]] = bi[r];
        }
    __syncthreads();

    // combine 4 wave-partials (ascending var ranges keep first-index semantics)
    float mx[16]; int kk[16];
#pragma unroll
    for (int r = 0; r < 16; ++r) {
        mx[r] = smaxA[rowv[r]]; kk[r] = sidxA[rowv[r]];
#pragma unroll
        for (int w2 = 1; w2 < 4; ++w2) {
            float mv = smaxA[w2 * 32 + rowv[r]];
            int   iv = sidxA[w2 * 32 + rowv[r]];
            if (mv > mx[r] || (mv == mx[r] && iv < kk[r])) { mx[r] = mv; kk[r] = iv; }
        }
    }

    // exp + row-sum
    float rs[16];
#pragma unroll
    for (int r = 0; r < 16; ++r) rs[r] = 0.0f;
#pragma unroll
    for (int p = 0; p < 4; ++p)
#pragma unroll
        for (int r = 0; r < 16; ++r) {
            v[p][r] = __expf(v[p][r] - mx[r]);
            rs[r] += v[p][r];
        }
#pragma unroll
    for (int off = 16; off >= 1; off >>= 1)
#pragma unroll
        for (int r = 0; r < 16; ++r) rs[r] += __shfl_xor(rs[r], off, 64);
    if (lm == 0)
#pragma unroll
        for (int r = 0; r < 16; ++r) ssumA[wave * 32 + rowv[r]] = rs[r];
    if (wave == 0 && lm == 0)
#pragma unroll
        for (int r = 0; r < 16; ++r) skidx[rowv[r]] = kk[r];
    __syncthreads();

    float inv_[16];
#pragma unroll
    for (int r = 0; r < 16; ++r)
        inv_[r] = 1.0f / (ssumA[rowv[r]] + ssumA[32 + rowv[r]] +
                          ssumA[64 + rowv[r]] + ssumA[96 + rowv[r]]);

    // soft stores + masked column partial sums
    float ca[4] = {0.f, 0.f, 0.f, 0.f};
#pragma unroll
    for (int p = 0; p < 4; ++p)
#pragma unroll
        for (int r = 0; r < 16; ++r) {
            float sv = v[p][r] * inv_[r];
            soft[(size_t)(m0 + rowv[r]) * NV + wave * 128 + p * 32 + lm] = sv;
            ca[p] += sv * mk[r];
        }
#pragma unroll
    for (int p = 0; p < 4; ++p) ca[p] += __shfl_xor(ca[p], 32, 64);
    if (hi == 0)
#pragma unroll
        for (int p = 0; p < 4; ++p) scol[wave * 128 + p * 32 + lm] = ca[p];

    // one-hot + codebook gather (skidx valid since last barrier)
#pragma unroll
    for (int s = 0; s < 8; ++s) {
        const int tk = wave * 8 + s;
        const int k  = skidx[tk];
        float* grow = gumbel + (size_t)(m0 + tk) * NV;   // 4B-aligned base
#pragma unroll
        for (int j = 0; j < 8; ++j)
            grow[j * 64 + lane] = (j * 64 + lane == k) ? 1.0f : 0.0f;
        float4 cv;
        if (k == 0) { cv.x = cv.y = cv.z = cv.w = 0.0f; }
        else        { cv = *(const float4*)(codebook + (size_t)k * VD + lane * 4); }
        *(float4*)(outp + (size_t)(m0 + tk) * VD + lane * 4) = cv;
    }

    __syncthreads();   // scol complete
    atomicAdd(&sums[tid],       scol[tid]);
    atomicAdd(&sums[tid + 256], scol[tid + 256]);
    if (wave == 0) {
        float mv = (lane < 32) ? smask[lane] : 0.0f;
#pragma unroll
        for (int off = 32; off >= 1; off >>= 1) mv += __shfl_xor(mv, off, 64);
        if (lane == 0) atomicAdd(&sums[NV], mv);
    }
}

// ---------------------------------------------------------------------------
// K2: perplexity from 513 accumulated floats
// ---------------------------------------------------------------------------
__global__ __launch_bounds__(256) void k_perp(const float* __restrict__ sums,
                                              float* __restrict__ perp) {
    __shared__ float red[256];
    const int tid = threadIdx.x;
    const float msum = sums[NV];
    float ent = 0.f;
    for (int c = tid; c < NV; c += 256) {
        const float a = sums[c] / msum;
        ent += a * logf(a + 1e-7f);
    }
    red[tid] = ent;
    __syncthreads();
    for (int s = 128; s > 0; s >>= 1) {
        if (tid < s) red[tid] += red[tid + s];
        __syncthreads();
    }
    if (tid == 0) perp[0] = expf(-red[0]);
}

// ---------------------------------------------------------------------------
extern "C" void kernel_launch(void* const* d_in, const int* in_sizes, int n_in,
                              void* d_out, int out_size, void* d_ws, size_t ws_size,
                              hipStream_t stream) {
    const float* x    = (const float*)d_in[0];
    const float* mask = (const float*)d_in[1];
    const float* W    = (const float*)d_in[2];
    const float* cb   = (const float*)d_in[3];

    float* out    = (float*)d_out;
    float* soft   = out + SOFT_OFF;
    float* perp   = out + PERP_OFF;
    float* gumbel = out + GUM_OFF;

    _Float16* whi = (_Float16*)d_ws;
    _Float16* wlo = whi + WLO_ELEM_OFF;
    float* sums   = (float*)((char*)d_ws + SUMS_BYTE_OFF);

    hipMemsetAsync(sums, 0, (NV + 1) * sizeof(float), stream);

    k_wsplit<<<NV * DIM / (256 * 4), 256, 0, stream>>>(W, whi, wlo);
    k_fused<<<NTOK / 32, 256, 0, stream>>>(x, whi, wlo, mask, cb, soft, gumbel, out, sums);
    k_perp<<<1, 256, 0, stream>>>(sums, perp);
}